// Round 1
// baseline (77.710 us; speedup 1.0000x reference)
//
#include <hip/hip_runtime.h>

#define VOCAB 100000
#define EMBED 128
#define BATCH 16384
#define WIN 10
#define NEG 10

// One 64-lane wave per batch element. Each lane owns 2 consecutive embedding
// floats (float2): 64 lanes x 8B = 512B = one full table row per wave-load,
// perfectly coalesced. 4 waves per 256-thread block.
__global__ __launch_bounds__(256) void cbow_loss_kernel(
    const float* __restrict__ target_table,   // [VOCAB][EMBED]
    const float* __restrict__ context_table,  // [VOCAB][EMBED]
    const int*   __restrict__ context,        // [B]
    const int*   __restrict__ target,         // [B][WIN]
    const int*   __restrict__ negatives,      // [B][NEG]
    float*       __restrict__ out)            // [1], pre-zeroed
{
    const int tid  = threadIdx.x;
    const int wave = tid >> 6;
    const int lane = tid & 63;
    const int b    = blockIdx.x * 4 + wave;

    const float2* tt2 = reinterpret_cast<const float2*>(target_table);
    const float2* ct2 = reinterpret_cast<const float2*>(context_table);

    // ---- trg = mean over window of target_table rows ----
    float2 trg = make_float2(0.f, 0.f);
    #pragma unroll
    for (int w = 0; w < WIN; ++w) {
        const int idx = target[b * WIN + w];
        const float2 v = tt2[(long long)idx * (EMBED / 2) + lane];
        trg.x += v.x;
        trg.y += v.y;
    }
    trg.x *= (1.0f / WIN);
    trg.y *= (1.0f / WIN);

    // ---- positive score partial ----
    const int cidx = context[b];
    const float2 cv = ct2[(long long)cidx * (EMBED / 2) + lane];
    float ps = trg.x * cv.x + trg.y * cv.y;

    // ---- negative score partials ----
    float ns[NEG];
    #pragma unroll
    for (int k = 0; k < NEG; ++k) {
        const int nidx = negatives[b * NEG + k];
        const float2 nv = ct2[(long long)nidx * (EMBED / 2) + lane];
        ns[k] = trg.x * nv.x + trg.y * nv.y;
    }

    // ---- butterfly reduce all 11 scores across the wave (interleaved for ILP) ----
    #pragma unroll
    for (int off = 32; off >= 1; off >>= 1) {
        ps += __shfl_xor(ps, off, 64);
        #pragma unroll
        for (int k = 0; k < NEG; ++k) ns[k] += __shfl_xor(ns[k], off, 64);
    }

    // ---- per-block accumulation ----
    __shared__ float bsum;
    if (tid == 0) bsum = 0.f;
    __syncthreads();

    if (lane == 0) {
        // pos_loss = -log_sigmoid(ps) = log1p(exp(-ps)) after clip
        float x = fminf(fmaxf(ps, -10.f), 10.f);
        float loss = log1pf(expf(-x));
        // neg_loss = sum_k -log_sigmoid(-ns[k]) = log1p(exp(ns[k])) after clip
        #pragma unroll
        for (int k = 0; k < NEG; ++k) {
            float s = fminf(fmaxf(ns[k], -10.f), 10.f);
            loss += log1pf(expf(s));
        }
        atomicAdd(&bsum, loss);
    }
    __syncthreads();

    if (tid == 0) {
        atomicAdd(out, bsum * (1.0f / BATCH));
    }
}

extern "C" void kernel_launch(void* const* d_in, const int* in_sizes, int n_in,
                              void* d_out, int out_size, void* d_ws, size_t ws_size,
                              hipStream_t stream) {
    const float* target_table  = (const float*)d_in[0];
    const float* context_table = (const float*)d_in[1];
    const int*   context       = (const int*)d_in[2];
    const int*   target        = (const int*)d_in[3];
    const int*   negatives     = (const int*)d_in[4];
    float* out = (float*)d_out;

    // Zero the accumulator (graph-capture-safe async memset).
    hipMemsetAsync(out, 0, sizeof(float), stream);

    cbow_loss_kernel<<<BATCH / 4, 256, 0, stream>>>(
        target_table, context_table, context, target, negatives, out);
}

// Round 2
// 45.850 us; speedup vs baseline: 1.6949x; 1.6949x over previous
//
#include <hip/hip_runtime.h>

#define VOCAB 100000
#define EMBED 128
#define BATCH 16384
#define WIN 10
#define NEG 10

// 16 lanes per batch element, 4 elements per 64-lane wave, 16 elements per
// 256-thread block. Each lane owns 8 consecutive floats (2x float4 = 32B);
// a row gather = 16 lanes x 32B = 512B contiguous, and one load instruction
// services 4 different rows (one per 16-lane group).
__global__ __launch_bounds__(256) void cbow_loss_kernel(
    const float* __restrict__ target_table,   // [VOCAB][EMBED]
    const float* __restrict__ context_table,  // [VOCAB][EMBED]
    const int*   __restrict__ context,        // [B]
    const int*   __restrict__ target,         // [B][WIN]
    const int*   __restrict__ negatives,      // [B][NEG]
    float*       __restrict__ out)            // [1], pre-zeroed
{
    const int tid    = threadIdx.x;
    const int lane16 = tid & 15;   // position within 16-lane group
    const int grp    = tid >> 4;   // group id within block (0..15)
    const int b      = blockIdx.x * 16 + grp;

    const float4* tt4 = reinterpret_cast<const float4*>(target_table);
    const float4* ct4 = reinterpret_cast<const float4*>(context_table);
    // One row = EMBED/4 = 32 float4s. Lane owns float4s [lane16*2, lane16*2+1].
    const int lo = lane16 * 2;

    // ---- load all 21 indices up front (broadcast loads within each group) ----
    int tidx[WIN];
    #pragma unroll
    for (int w = 0; w < WIN; ++w) tidx[w] = target[b * WIN + w];
    const int cidx = context[b];
    int nidx[NEG];
    #pragma unroll
    for (int k = 0; k < NEG; ++k) nidx[k] = negatives[b * NEG + k];

    // ---- trg = mean over window ----
    float4 t0 = make_float4(0.f, 0.f, 0.f, 0.f);
    float4 t1 = make_float4(0.f, 0.f, 0.f, 0.f);
    #pragma unroll
    for (int w = 0; w < WIN; ++w) {
        const float4* r = tt4 + (long long)tidx[w] * (EMBED / 4) + lo;
        const float4 a = r[0];
        const float4 c = r[1];
        t0.x += a.x; t0.y += a.y; t0.z += a.z; t0.w += a.w;
        t1.x += c.x; t1.y += c.y; t1.z += c.z; t1.w += c.w;
    }
    const float s = 1.0f / WIN;
    t0.x *= s; t0.y *= s; t0.z *= s; t0.w *= s;
    t1.x *= s; t1.y *= s; t1.z *= s; t1.w *= s;

    // ---- 11 dot-product partials (context first, then negatives) ----
    float sc[1 + NEG];
    {
        const float4* r = ct4 + (long long)cidx * (EMBED / 4) + lo;
        const float4 a = r[0];
        const float4 c = r[1];
        sc[0] = fmaf(t0.x, a.x, fmaf(t0.y, a.y, fmaf(t0.z, a.z, fmaf(t0.w, a.w,
                fmaf(t1.x, c.x, fmaf(t1.y, c.y, fmaf(t1.z, c.z, t1.w * c.w)))))));
    }
    #pragma unroll
    for (int k = 0; k < NEG; ++k) {
        const float4* r = ct4 + (long long)nidx[k] * (EMBED / 4) + lo;
        const float4 a = r[0];
        const float4 c = r[1];
        sc[1 + k] = fmaf(t0.x, a.x, fmaf(t0.y, a.y, fmaf(t0.z, a.z, fmaf(t0.w, a.w,
                    fmaf(t1.x, c.x, fmaf(t1.y, c.y, fmaf(t1.z, c.z, t1.w * c.w)))))));
    }

    // ---- butterfly reduce within each 16-lane group (4 steps, 11 values) ----
    #pragma unroll
    for (int off = 8; off >= 1; off >>= 1) {
        #pragma unroll
        for (int i = 0; i < 1 + NEG; ++i) sc[i] += __shfl_xor(sc[i], off, 16);
    }

    // ---- per-block accumulation ----
    __shared__ float bsum;
    if (tid == 0) bsum = 0.f;
    __syncthreads();

    if (lane16 == 0) {
        // pos_loss = log1p(exp(-clip(ps)))
        float x = fminf(fmaxf(sc[0], -10.f), 10.f);
        float loss = log1pf(expf(-x));
        // neg_loss = sum_k log1p(exp(clip(ns)))
        #pragma unroll
        for (int k = 0; k < NEG; ++k) {
            float y = fminf(fmaxf(sc[1 + k], -10.f), 10.f);
            loss += log1pf(expf(y));
        }
        atomicAdd(&bsum, loss);
    }
    __syncthreads();

    if (tid == 0) {
        atomicAdd(out, bsum * (1.0f / BATCH));
    }
}

extern "C" void kernel_launch(void* const* d_in, const int* in_sizes, int n_in,
                              void* d_out, int out_size, void* d_ws, size_t ws_size,
                              hipStream_t stream) {
    const float* target_table  = (const float*)d_in[0];
    const float* context_table = (const float*)d_in[1];
    const int*   context       = (const int*)d_in[2];
    const int*   target        = (const int*)d_in[3];
    const int*   negatives     = (const int*)d_in[4];
    float* out = (float*)d_out;

    hipMemsetAsync(out, 0, sizeof(float), stream);

    cbow_loss_kernel<<<BATCH / 16, 256, 0, stream>>>(
        target_table, context_table, context, target, negatives, out);
}

// Round 3
// 44.234 us; speedup vs baseline: 1.7568x; 1.0365x over previous
//
#include <hip/hip_runtime.h>

#define VOCAB 100000
#define EMBED 128
#define BATCH 16384
#define WIN 10
#define NEG 10

// 16 lanes per batch element, 4 elements per 64-lane wave, 16 elements per
// 256-thread block. Each lane owns 8 consecutive floats (2x float4 = 32B).
// Loads are structured load-ALL-rows-then-reduce so ~20 float4 gathers are
// in flight per wave (MLP), instead of ~4 with accumulate-as-you-go.
// __launch_bounds__(256,4) caps VGPR at 128 = still 16 waves/CU resident.
__global__ __launch_bounds__(256, 4) void cbow_loss_kernel(
    const float* __restrict__ target_table,   // [VOCAB][EMBED]
    const float* __restrict__ context_table,  // [VOCAB][EMBED]
    const int*   __restrict__ context,        // [B]
    const int*   __restrict__ target,         // [B][WIN]
    const int*   __restrict__ negatives,      // [B][NEG]
    float*       __restrict__ out)            // [1], pre-zeroed
{
    const int tid    = threadIdx.x;
    const int lane16 = tid & 15;
    const int grp    = tid >> 4;
    const int b      = blockIdx.x * 16 + grp;

    const float4* tt4 = reinterpret_cast<const float4*>(target_table);
    const float4* ct4 = reinterpret_cast<const float4*>(context_table);
    const int lo = lane16 * 2;  // row = 32 float4s; lane owns [lo, lo+1]

    // ---- all 21 indices up front (independent loads) ----
    int tidx[WIN];
    #pragma unroll
    for (int w = 0; w < WIN; ++w) tidx[w] = target[b * WIN + w];
    const int cidx = context[b];
    int nidx[NEG];
    #pragma unroll
    for (int k = 0; k < NEG; ++k) nidx[k] = negatives[b * NEG + k];

    // ---- phase 1: load ALL window rows, then tree-sum ----
    float4 wa[WIN], wb[WIN];
    #pragma unroll
    for (int w = 0; w < WIN; ++w) {
        const float4* r = tt4 + (long long)tidx[w] * (EMBED / 4) + lo;
        wa[w] = r[0];
        wb[w] = r[1];
    }
    // pairwise tree reduction (shorter dep chains)
    #pragma unroll
    for (int stride = 1; stride < WIN; stride <<= 1) {
        #pragma unroll
        for (int w = 0; w + stride < WIN; w += 2 * stride) {
            wa[w].x += wa[w + stride].x; wa[w].y += wa[w + stride].y;
            wa[w].z += wa[w + stride].z; wa[w].w += wa[w + stride].w;
            wb[w].x += wb[w + stride].x; wb[w].y += wb[w + stride].y;
            wb[w].z += wb[w + stride].z; wb[w].w += wb[w + stride].w;
        }
    }
    const float s = 1.0f / WIN;
    float4 t0 = wa[0], t1 = wb[0];
    t0.x *= s; t0.y *= s; t0.z *= s; t0.w *= s;
    t1.x *= s; t1.y *= s; t1.z *= s; t1.w *= s;

    // ---- phase 2: load ALL 11 score rows, then dot ----
    float4 ca[1 + NEG], cb[1 + NEG];
    {
        const float4* r = ct4 + (long long)cidx * (EMBED / 4) + lo;
        ca[0] = r[0];
        cb[0] = r[1];
    }
    #pragma unroll
    for (int k = 0; k < NEG; ++k) {
        const float4* r = ct4 + (long long)nidx[k] * (EMBED / 4) + lo;
        ca[1 + k] = r[0];
        cb[1 + k] = r[1];
    }

    float sc[1 + NEG];
    #pragma unroll
    for (int i = 0; i < 1 + NEG; ++i) {
        sc[i] = fmaf(t0.x, ca[i].x, fmaf(t0.y, ca[i].y,
                fmaf(t0.z, ca[i].z, fmaf(t0.w, ca[i].w,
                fmaf(t1.x, cb[i].x, fmaf(t1.y, cb[i].y,
                fmaf(t1.z, cb[i].z, t1.w * cb[i].w)))))));
    }

    // ---- butterfly reduce within 16-lane group (4 steps, 11 values) ----
    #pragma unroll
    for (int off = 8; off >= 1; off >>= 1) {
        #pragma unroll
        for (int i = 0; i < 1 + NEG; ++i) sc[i] += __shfl_xor(sc[i], off, 16);
    }

    // ---- per-block accumulation ----
    __shared__ float bsum;
    if (tid == 0) bsum = 0.f;
    __syncthreads();

    if (lane16 == 0) {
        float x = fminf(fmaxf(sc[0], -10.f), 10.f);
        float loss = log1pf(expf(-x));
        #pragma unroll
        for (int k = 0; k < NEG; ++k) {
            float y = fminf(fmaxf(sc[1 + k], -10.f), 10.f);
            loss += log1pf(expf(y));
        }
        atomicAdd(&bsum, loss);
    }
    __syncthreads();

    if (tid == 0) {
        atomicAdd(out, bsum * (1.0f / BATCH));
    }
}

extern "C" void kernel_launch(void* const* d_in, const int* in_sizes, int n_in,
                              void* d_out, int out_size, void* d_ws, size_t ws_size,
                              hipStream_t stream) {
    const float* target_table  = (const float*)d_in[0];
    const float* context_table = (const float*)d_in[1];
    const int*   context       = (const int*)d_in[2];
    const int*   target        = (const int*)d_in[3];
    const int*   negatives     = (const int*)d_in[4];
    float* out = (float*)d_out;

    hipMemsetAsync(out, 0, sizeof(float), stream);

    cbow_loss_kernel<<<BATCH / 16, 256, 0, stream>>>(
        target_table, context_table, context, target, negatives, out);
}